// Round 11
// baseline (1268.795 us; speedup 1.0000x reference)
//
#include <hip/hip_runtime.h>
#include <hip/hip_bf16.h>
#include <math.h>

#define NN 50000
#define NE 800000
#define FF 64
#define ZD 192

typedef __attribute__((ext_vector_type(8))) short bf16x8;
typedef __attribute__((ext_vector_type(4))) float f32x4;

__device__ __forceinline__ short f2bs(float f){
  union { __hip_bfloat16 h; short s; } u; u.h = __float2bfloat16(f); return u.s;
}
__device__ __forceinline__ unsigned packbf(float a, float b){
  return ((unsigned)(unsigned short)f2bs(b) << 16) | (unsigned)(unsigned short)f2bs(a);
}
__device__ __forceinline__ float lo16f(unsigned u){ union{unsigned u; float f;} v; v.u = u << 16; return v.f; }
__device__ __forceinline__ float hi16f(unsigned u){ union{unsigned u; float f;} v; v.u = u & 0xFFFF0000u; return v.f; }
__device__ __forceinline__ float sigm(float x){ return 1.0f/(1.0f+__expf(-x)); }
__device__ __forceinline__ float sofp(float x){ return fmaxf(x,0.0f)+__logf(1.0f+__expf(-fabsf(x))); }
__device__ __forceinline__ float fsilu(float x){ return x/(1.0f+__expf(-x)); }

// ---------------------------------------------------------------------------
// k1: aout=atom copy + per-node gating-linear parts via MFMA (packed bf16).
// ---------------------------------------------------------------------------
__global__ __launch_bounds__(256) void k1_node_pre(
    const float* __restrict__ atom,
    const float* __restrict__ wf, const float* __restrict__ ws,
    unsigned* __restrict__ P2u, float* __restrict__ aout)
{
  int tid0 = blockIdx.x * 256 + threadIdx.x;
  int nthr = gridDim.x * 256;
  const float4* a4 = (const float4*)atom;
  float4* o4 = (float4*)aout;
  for (int i = tid0; i < NN*FF/4; i += nthr) o4[i] = a4[i];

  int lane = threadIdx.x & 63;
  int c = lane & 15, kb = lane >> 4;
  int wid = blockIdx.x * 4 + (threadIdx.x >> 6);
  int nw = gridDim.x * 4;
  for (int g = wid; g < NN/16; g += nw) {
    int n0 = g * 16;
    const float* arow = &atom[(size_t)(n0 + c) * FF + kb*8];
    bf16x8 A0, A1;
    #pragma unroll
    for (int j = 0; j < 8; j++) { A0[j] = f2bs(arow[j]); A1[j] = f2bs(arow[32+j]); }
    f32x4 acc[16];
    #pragma unroll
    for (int t = 0; t < 16; t++) acc[t] = (f32x4){0,0,0,0};
    #pragma unroll
    for (int t = 0; t < 16; t++) {
      int og = t*16 + c;
      const float* src;
      if (t < 4)       src = &wf[og*ZD];
      else if (t < 8)  src = &wf[(og-64)*ZD + 64];
      else if (t < 12) src = &ws[(og-128)*ZD];
      else             src = &ws[(og-192)*ZD + 64];
      bf16x8 B0, B1;
      #pragma unroll
      for (int j = 0; j < 8; j++) { B0[j] = f2bs(src[kb*8+j]); B1[j] = f2bs(src[32+kb*8+j]); }
      acc[t] = __builtin_amdgcn_mfma_f32_16x16x32_bf16(A0, B0, acc[t], 0,0,0);
      acc[t] = __builtin_amdgcn_mfma_f32_16x16x32_bf16(A1, B1, acc[t], 0,0,0);
    }
    #pragma unroll
    for (int t = 0; t < 8; t++) {
      #pragma unroll
      for (int r = 0; r < 4; r++) {
        int n = n0 + kb*4 + r;
        P2u[(size_t)n*128 + t*16 + c] = packbf(acc[t][r], acc[t+8][r]);
      }
    }
  }
}

// ---------------------------------------------------------------------------
// k2 core, templated for ablation.  V=0 real; V=1 no-atomic; V=2 L2-window
// gathers; V=3 no transcendentals; V=4 no f2bs/MFMA (acc fed from loads).
// Variants V>0 write scratch only.
// ---------------------------------------------------------------------------
template<int V>
__global__ __launch_bounds__(256) void k2v(
    const int* __restrict__ eidx, const float* __restrict__ efea,
    const float* __restrict__ dist,
    const float* __restrict__ wf, const float* __restrict__ ws,
    const float* __restrict__ bfb, const float* __restrict__ bsb,
    const float* __restrict__ fc1w,
    const unsigned* __restrict__ P2u, float* __restrict__ aout,
    float* __restrict__ eout)
{
  int tid = threadIdx.x;
  int lane = tid & 63;
  int lw = tid >> 6;
  int c = lane & 15, kb = lane >> 4;

  bf16x8 Bf[9][2];
  #pragma unroll
  for (int t = 0; t < 9; t++) {
    int og = t*16 + c;
    const float* src = nullptr;
    if (t < 4)            src = &wf[og*ZD + 128];
    else if (t < 8)       src = &ws[(og-64)*ZD + 128];
    else if (og-128 < 14) src = &fc1w[(og-128)*ZD + 128];
    #pragma unroll
    for (int f = 0; f < 2; f++) {
      bf16x8 r;
      #pragma unroll
      for (int j = 0; j < 8; j++) r[j] = src ? f2bs(src[f*32 + kb*8 + j]) : (short)0;
      Bf[t][f] = r;
    }
  }
  float bfo[4], bso[4];
  #pragma unroll
  for (int t = 0; t < 4; t++) { bfo[t] = bfb[t*16+c]; bso[t] = bsb[t*16+c]; }

  const int ngroups = NE/16;
  int wid = blockIdx.x*4 + lw;
  int nw = gridDim.x*4;

  int pS = 0, pD = 0; float pDe = 0.f;
  float4 pe0, pe1, pe2, pe3;
  int g = wid;
  if (g < ngroups) {
    int e0 = g*16;
    pS  = eidx[e0 + c];
    pD  = eidx[NE + e0 + c];
    pDe = dist[e0 + c];
    const float4* er = (const float4*)&efea[(size_t)(e0 + c)*FF];
    pe0 = er[kb*2]; pe1 = er[kb*2+1]; pe2 = er[8+kb*2]; pe3 = er[8+kb*2+1];
  }

  for (; g < ngroups; g += nw) {
    int e0 = g*16;
    bf16x8 A0, A1;
    if constexpr (V != 4) {
      A0[0]=f2bs(pe0.x); A0[1]=f2bs(pe0.y); A0[2]=f2bs(pe0.z); A0[3]=f2bs(pe0.w);
      A0[4]=f2bs(pe1.x); A0[5]=f2bs(pe1.y); A0[6]=f2bs(pe1.z); A0[7]=f2bs(pe1.w);
      A1[0]=f2bs(pe2.x); A1[1]=f2bs(pe2.y); A1[2]=f2bs(pe2.z); A1[3]=f2bs(pe2.w);
      A1[4]=f2bs(pe3.x); A1[5]=f2bs(pe3.y); A1[6]=f2bs(pe3.z); A1[7]=f2bs(pe3.w);
    }
    int sNv = pS, dNv = pD; float dev = pDe;
    float wdv = __expf(-dev*dev*(1.0f/18.0f));
    int sN[4], dN[4]; float wd[4];
    #pragma unroll
    for (int r = 0; r < 4; r++) {
      sN[r] = __shfl(sNv, kb*4 + r, 64);
      dN[r] = __shfl(dNv, kb*4 + r, 64);
      wd[r] = __shfl(wdv, kb*4 + r, 64);
    }
    // P2 gathers (V2: window-masked -> L2-resident, same instruction stream)
    unsigned vdu[4][4], vsu[4][4];
    #pragma unroll
    for (int r = 0; r < 4; r++) {
      int dn = (V == 2) ? (dN[r] & 511) : dN[r];
      int sn = (V == 2) ? (sN[r] & 511) : sN[r];
      #pragma unroll
      for (int t = 0; t < 4; t++) {
        vdu[r][t] = P2u[(size_t)dn*128 + t*16 + c];
        vsu[r][t] = P2u[(size_t)sn*128 + 64 + t*16 + c];
      }
    }
    // prefetch g+1
    {
      int gp = g + nw; if (gp >= ngroups) gp = g;
      int e0p = gp*16;
      pS  = eidx[e0p + c];
      pD  = eidx[NE + e0p + c];
      pDe = dist[e0p + c];
      const float4* erp = (const float4*)&efea[(size_t)(e0p + c)*FF];
      pe0 = erp[kb*2]; pe1 = erp[kb*2+1]; pe2 = erp[8+kb*2]; pe3 = erp[8+kb*2+1];
    }
    f32x4 acc[9];
    if constexpr (V != 4) {
      #pragma unroll
      for (int t = 0; t < 9; t++) acc[t] = (f32x4){0,0,0,0};
      #pragma unroll
      for (int t = 0; t < 9; t++) {
        acc[t] = __builtin_amdgcn_mfma_f32_16x16x32_bf16(A0, Bf[t][0], acc[t], 0,0,0);
        acc[t] = __builtin_amdgcn_mfma_f32_16x16x32_bf16(A1, Bf[t][1], acc[t], 0,0,0);
      }
    } else {
      // keep prefetched efea values live without conversion/MFMA
      #pragma unroll
      for (int t = 0; t < 9; t++)
        acc[t] = (f32x4){pe0.x + t, pe1.y, pe2.z, pe3.w};
    }
    if (c < 14) {
      #pragma unroll
      for (int r = 0; r < 4; r++)
        eout[(size_t)(e0 + kb*4 + r)*FF + c] = acc[8][r];
    }
    #pragma unroll
    for (int r = 0; r < 4; r++) {
      #pragma unroll
      for (int t = 0; t < 4; t++) {
        float zf = acc[t][r]   + lo16f(vdu[r][t]) + lo16f(vsu[r][t]) + bfo[t];
        float zs = acc[t+4][r] + hi16f(vdu[r][t]) + hi16f(vsu[r][t]) + bso[t];
        float m;
        if constexpr (V == 3) m = (zf + zs) * wd[r];
        else                  m = sigm(zf) * sofp(zs) * wd[r];
        if constexpr (V == 1)
          aout[(size_t)dN[r]*FF + t*16 + c] = m;
        else
          atomicAdd(&aout[(size_t)dN[r]*FF + t*16 + c], m);
      }
    }
  }
}

// ---------------------------------------------------------------------------
// k3: per-node fc1 partials on UPDATED node features.
// ---------------------------------------------------------------------------
__global__ __launch_bounds__(256) void k3_cpre(
    const float* __restrict__ aout, const float* __restrict__ fc1w,
    float* __restrict__ C)
{
  __shared__ float wT[64*32];
  __shared__ float xs[4][64];
  int tid = threadIdx.x;
  for (int i = tid; i < 64*28; i += 256) {
    int k = i / 28, j = i % 28;
    wT[k*32 + j] = (j < 14) ? fc1w[j*ZD + k] : fc1w[(j-14)*ZD + 64 + k];
  }
  __syncthreads();
  int o  = tid & 63;
  int lw = tid >> 6;
  int wid = blockIdx.x * 4 + lw;
  int nw  = gridDim.x * 4;
  for (int n = wid; n < NN; n += nw) {
    xs[lw][o] = aout[(size_t)n*FF + o];
    float acc = 0.f;
    if (o < 28) {
      for (int k = 0; k < 64; k++) acc += xs[lw][k] * wT[k*32 + o];
      C[n*28 + o] = acc;
    }
  }
}

// ---------------------------------------------------------------------------
// k5: edge-update MLP. 8 edges/wave. h-edge-part read from eout stash.
// ---------------------------------------------------------------------------
__global__ __launch_bounds__(256) void k5_edge_mlp(
    const int* __restrict__ eidx,
    const float* __restrict__ fc1b,
    const float* __restrict__ fc2w, const float* __restrict__ fc2b,
    const float* __restrict__ C, float* __restrict__ eout)
{
  __shared__ float w2T[14*64];
  __shared__ float hs[4][128];
  int tid = threadIdx.x;
  for (int i = tid; i < 14*64; i += 256) {
    int j = i >> 6, o = i & 63;
    w2T[i] = fc2w[o*14 + j];
  }
  __syncthreads();
  int o  = tid & 63;
  int lw = tid >> 6;
  int j4 = o >> 2, q = o & 3;
  int wid = blockIdx.x*4 + lw;
  int nw  = gridDim.x*4;
  for (int g = wid; g < NE/8; g += nw) {
    int e0 = g*8;
    #pragma unroll
    for (int pass = 0; pass < 2; pass++) {
      int ee = pass*4 + q;
      int e = e0 + ee;
      if (j4 < 14) {
        int sN = eidx[e], dN = eidx[NE+e];
        float h = eout[(size_t)e*FF + j4] + C[sN*28 + j4] + C[dN*28 + 14 + j4] + fc1b[j4];
        hs[lw][ee*16 + j4] = fsilu(h);
      }
    }
    asm volatile("s_waitcnt lgkmcnt(0)" ::: "memory");  // in-wave LDS RAW
    float b2 = fc2b[o];
    #pragma unroll
    for (int ee = 0; ee < 8; ee++) {
      float acc = b2;
      #pragma unroll
      for (int jj = 0; jj < 14; jj++)
        acc += w2T[jj*64 + o] * hs[lw][ee*16 + jj];
      eout[(size_t)(e0 + ee)*FF + o] = fsilu(acc);
    }
  }
}

// ---------------------------------------------------------------------------
extern "C" void kernel_launch(void* const* d_in, const int* in_sizes, int n_in,
                              void* d_out, int out_size, void* d_ws, size_t ws_size,
                              hipStream_t stream) {
  const float* atom  = (const float*)d_in[0];
  const int*   eidx  = (const int*)  d_in[1];
  const float* efea  = (const float*)d_in[2];
  const float* dist  = (const float*)d_in[4];
  const float* wf    = (const float*)d_in[6];
  const float* bf    = (const float*)d_in[7];
  const float* ws    = (const float*)d_in[8];
  const float* bs    = (const float*)d_in[9];
  const float* fc1w  = (const float*)d_in[10];
  const float* fc1b  = (const float*)d_in[11];
  const float* fc2w  = (const float*)d_in[12];
  const float* fc2b  = (const float*)d_in[13];

  float* aout = (float*)d_out;                 // [50000, 64]
  float* eout = aout + (size_t)NN * FF;        // [800000, 64]

  char* wp = (char*)d_ws;
  unsigned* P2u  = (unsigned*)wp;  wp += (size_t)NN * 128 * 4;   // 25.6 MB
  float*    C    = (float*)wp;     wp += (size_t)NN * 28 * 4;    //  5.6 MB
  float*    scA  = (float*)wp;     wp += (size_t)NN * FF * 4;    // 12.8 MB
  float*    scE  = (float*)wp;     wp += (size_t)NE * FF * 4;    // 204.8 MB
  bool have_scratch = ((size_t)(wp - (char*)d_ws)) <= ws_size;

  hipLaunchKernelGGL(k1_node_pre, dim3(512), dim3(256), 0, stream,
                     atom, wf, ws, P2u, aout);
  if (have_scratch) {
    // --- ablation variants (scratch-only, diagnostic) ---
    k2v<1><<<dim3(1024), dim3(256), 0, stream>>>(eidx, efea, dist, wf, ws, bf, bs, fc1w, P2u, scA, scE);
    k2v<2><<<dim3(1024), dim3(256), 0, stream>>>(eidx, efea, dist, wf, ws, bf, bs, fc1w, P2u, scA, scE);
    k2v<3><<<dim3(1024), dim3(256), 0, stream>>>(eidx, efea, dist, wf, ws, bf, bs, fc1w, P2u, scA, scE);
    k2v<4><<<dim3(1024), dim3(256), 0, stream>>>(eidx, efea, dist, wf, ws, bf, bs, fc1w, P2u, scA, scE);
  }
  // --- real pipeline (identical to R10) ---
  k2v<0><<<dim3(1024), dim3(256), 0, stream>>>(eidx, efea, dist, wf, ws, bf, bs, fc1w, P2u, aout, eout);
  hipLaunchKernelGGL(k3_cpre, dim3(512), dim3(256), 0, stream,
                     aout, fc1w, C);
  hipLaunchKernelGGL(k5_edge_mlp, dim3(2048), dim3(256), 0, stream,
                     eidx, fc1b, fc2w, fc2b, C, eout);
}

// Round 12
// 441.867 us; speedup vs baseline: 2.8714x; 2.8714x over previous
//
#include <hip/hip_runtime.h>
#include <hip/hip_bf16.h>
#include <math.h>

#define NN 50000
#define NE 800000
#define FF 64
#define ZD 192

typedef __attribute__((ext_vector_type(8))) short bf16x8;
typedef __attribute__((ext_vector_type(4))) float f32x4;
typedef __attribute__((ext_vector_type(4))) float f4v;

__device__ __forceinline__ short f2bs(float f){
  union { __hip_bfloat16 h; short s; } u; u.h = __float2bfloat16(f); return u.s;
}
__device__ __forceinline__ unsigned packbf(float a, float b){
  return ((unsigned)(unsigned short)f2bs(b) << 16) | (unsigned)(unsigned short)f2bs(a);
}
__device__ __forceinline__ float lo16f(unsigned u){ union{unsigned u; float f;} v; v.u = u << 16; return v.f; }
__device__ __forceinline__ float hi16f(unsigned u){ union{unsigned u; float f;} v; v.u = u & 0xFFFF0000u; return v.f; }
__device__ __forceinline__ float sigm(float x){ return 1.0f/(1.0f+__expf(-x)); }
__device__ __forceinline__ float sofp(float x){ return fmaxf(x,0.0f)+__logf(1.0f+__expf(-fabsf(x))); }
__device__ __forceinline__ float fsilu(float x){ return x/(1.0f+__expf(-x)); }

// ---------------------------------------------------------------------------
// k1: aout=atom copy + per-node gating-linear parts via MFMA (packed bf16).
//  P2u stays cached (read-many by k2's gathers).
// ---------------------------------------------------------------------------
__global__ __launch_bounds__(256) void k1_node_pre(
    const float* __restrict__ atom,
    const float* __restrict__ wf, const float* __restrict__ ws,
    unsigned* __restrict__ P2u, float* __restrict__ aout)
{
  int tid0 = blockIdx.x * 256 + threadIdx.x;
  int nthr = gridDim.x * 256;
  const float4* a4 = (const float4*)atom;
  float4* o4 = (float4*)aout;
  for (int i = tid0; i < NN*FF/4; i += nthr) o4[i] = a4[i];

  int lane = threadIdx.x & 63;
  int c = lane & 15, kb = lane >> 4;
  int wid = blockIdx.x * 4 + (threadIdx.x >> 6);
  int nw = gridDim.x * 4;
  for (int g = wid; g < NN/16; g += nw) {
    int n0 = g * 16;
    const float* arow = &atom[(size_t)(n0 + c) * FF + kb*8];
    bf16x8 A0, A1;
    #pragma unroll
    for (int j = 0; j < 8; j++) { A0[j] = f2bs(arow[j]); A1[j] = f2bs(arow[32+j]); }
    f32x4 acc[16];
    #pragma unroll
    for (int t = 0; t < 16; t++) acc[t] = (f32x4){0,0,0,0};
    #pragma unroll
    for (int t = 0; t < 16; t++) {
      int og = t*16 + c;
      const float* src;
      if (t < 4)       src = &wf[og*ZD];
      else if (t < 8)  src = &wf[(og-64)*ZD + 64];
      else if (t < 12) src = &ws[(og-128)*ZD];
      else             src = &ws[(og-192)*ZD + 64];
      bf16x8 B0, B1;
      #pragma unroll
      for (int j = 0; j < 8; j++) { B0[j] = f2bs(src[kb*8+j]); B1[j] = f2bs(src[32+kb*8+j]); }
      acc[t] = __builtin_amdgcn_mfma_f32_16x16x32_bf16(A0, B0, acc[t], 0,0,0);
      acc[t] = __builtin_amdgcn_mfma_f32_16x16x32_bf16(A1, B1, acc[t], 0,0,0);
    }
    #pragma unroll
    for (int t = 0; t < 8; t++) {
      #pragma unroll
      for (int r = 0; r < 4; r++) {
        int n = n0 + kb*4 + r;
        P2u[(size_t)n*128 + t*16 + c] = packbf(acc[t][r], acc[t+8][r]);
      }
    }
  }
}

// ---------------------------------------------------------------------------
// k2: R7 shape (LDS weights -> 64 VGPR, ~43% occupancy, prefetch pipeline)
//  + NON-TEMPORAL stream accesses: efea/eidx/dist loads and the fc1-stash
//  store bypass L2 allocation, leaving L2 to P2u gathers + aout atomics.
// ---------------------------------------------------------------------------
__global__ __launch_bounds__(256, 4) void k2_msg(
    const int* __restrict__ eidx, const float* __restrict__ efea,
    const float* __restrict__ dist,
    const float* __restrict__ wf, const float* __restrict__ ws,
    const float* __restrict__ bfb, const float* __restrict__ bsb,
    const float* __restrict__ fc1w,
    const unsigned* __restrict__ P2u, float* __restrict__ aout,
    float* __restrict__ eout)
{
  __shared__ short BW[9][2][16][4][8];   // [tile][frag][c][kb][8] = 18 KB
  int tid = threadIdx.x;
  int lane = tid & 63;
  int lw = tid >> 6;
  int c = lane & 15, kb = lane >> 4;

  for (int i = tid; i < 9216; i += 256) {
    int j = i & 7, kbi = (i>>3)&3, ci = (i>>5)&15, fi = (i>>9)&1, t = i>>10;
    int og = t*16 + ci;
    const float* src = nullptr;
    if (t < 4)            src = &wf[og*ZD + 128];
    else if (t < 8)       src = &ws[(og-64)*ZD + 128];
    else if (og-128 < 14) src = &fc1w[(og-128)*ZD + 128];
    BW[t][fi][ci][kbi][j] = src ? f2bs(src[fi*32 + kbi*8 + j]) : (short)0;
  }
  float bfo[4], bso[4];
  #pragma unroll
  for (int t = 0; t < 4; t++) { bfo[t] = bfb[t*16+c]; bso[t] = bsb[t*16+c]; }
  __syncthreads();

  const int ngroups = NE/16;   // 50000, exact
  int wid = blockIdx.x*4 + lw;
  int nw = gridDim.x*4;

  // prefetched state for group g (non-temporal stream loads)
  int   pS = 0, pD = 0; float pDe = 0.f;
  f4v pe0, pe1, pe2, pe3;
  int g = wid;
  if (g < ngroups) {
    int e0 = g*16;
    pS  = __builtin_nontemporal_load(&eidx[e0 + c]);
    pD  = __builtin_nontemporal_load(&eidx[NE + e0 + c]);
    pDe = __builtin_nontemporal_load(&dist[e0 + c]);
    const f4v* er = (const f4v*)&efea[(size_t)(e0 + c)*FF];
    pe0 = __builtin_nontemporal_load(er + kb*2);
    pe1 = __builtin_nontemporal_load(er + kb*2 + 1);
    pe2 = __builtin_nontemporal_load(er + 8 + kb*2);
    pe3 = __builtin_nontemporal_load(er + 8 + kb*2 + 1);
  }

  for (; g < ngroups; g += nw) {
    int gp = g + nw; if (gp >= ngroups) gp = g;   // clamped redundant reload on last iter
    int e0 = g*16;
    // consume prefetched streams
    bf16x8 A0, A1;
    A0[0]=f2bs(pe0.x); A0[1]=f2bs(pe0.y); A0[2]=f2bs(pe0.z); A0[3]=f2bs(pe0.w);
    A0[4]=f2bs(pe1.x); A0[5]=f2bs(pe1.y); A0[6]=f2bs(pe1.z); A0[7]=f2bs(pe1.w);
    A1[0]=f2bs(pe2.x); A1[1]=f2bs(pe2.y); A1[2]=f2bs(pe2.z); A1[3]=f2bs(pe2.w);
    A1[4]=f2bs(pe3.x); A1[5]=f2bs(pe3.y); A1[6]=f2bs(pe3.z); A1[7]=f2bs(pe3.w);
    int sNv = pS, dNv = pD; float dev = pDe;
    float wdv = __expf(-dev*dev*(1.0f/18.0f));
    int sN[4], dN[4]; float wd[4];
    #pragma unroll
    for (int r = 0; r < 4; r++) {
      sN[r] = __shfl(sNv, kb*4 + r, 64);
      dN[r] = __shfl(dNv, kb*4 + r, 64);
      wd[r] = __shfl(wdv, kb*4 + r, 64);
    }
    // P2 gathers for g (cached; L2-resident now that streams bypass)
    unsigned vdu[4][4], vsu[4][4];
    #pragma unroll
    for (int r = 0; r < 4; r++) {
      #pragma unroll
      for (int t = 0; t < 4; t++) {
        vdu[r][t] = P2u[(size_t)dN[r]*128 + t*16 + c];
        vsu[r][t] = P2u[(size_t)sN[r]*128 + 64 + t*16 + c];
      }
    }
    // prefetch g+1 streams (non-temporal; issued AFTER gathers, BEFORE atomics)
    {
      int e0p = gp*16;
      pS  = __builtin_nontemporal_load(&eidx[e0p + c]);
      pD  = __builtin_nontemporal_load(&eidx[NE + e0p + c]);
      pDe = __builtin_nontemporal_load(&dist[e0p + c]);
      const f4v* erp = (const f4v*)&efea[(size_t)(e0p + c)*FF];
      pe0 = __builtin_nontemporal_load(erp + kb*2);
      pe1 = __builtin_nontemporal_load(erp + kb*2 + 1);
      pe2 = __builtin_nontemporal_load(erp + 8 + kb*2);
      pe3 = __builtin_nontemporal_load(erp + 8 + kb*2 + 1);
    }
    // MFMA over 9 output tiles, B from LDS
    f32x4 acc[9];
    #pragma unroll
    for (int t = 0; t < 9; t++) acc[t] = (f32x4){0,0,0,0};
    #pragma unroll
    for (int t = 0; t < 9; t++) {
      bf16x8 B0 = *(const bf16x8*)&BW[t][0][c][kb][0];
      bf16x8 B1 = *(const bf16x8*)&BW[t][1][c][kb][0];
      acc[t] = __builtin_amdgcn_mfma_f32_16x16x32_bf16(A0, B0, acc[t], 0,0,0);
      acc[t] = __builtin_amdgcn_mfma_f32_16x16x32_bf16(A1, B1, acc[t], 0,0,0);
    }
    // fc1-edge stash: non-temporal store (write-once, consumed by k5 from HBM)
    if (c < 14) {
      #pragma unroll
      for (int r = 0; r < 4; r++)
        __builtin_nontemporal_store(acc[8][r], &eout[(size_t)(e0 + kb*4 + r)*FF + c]);
    }
    // epilogue (waits on gathers; prefetch loads stay outstanding), then atomics
    #pragma unroll
    for (int r = 0; r < 4; r++) {
      #pragma unroll
      for (int t = 0; t < 4; t++) {
        float zf = acc[t][r]   + lo16f(vdu[r][t]) + lo16f(vsu[r][t]) + bfo[t];
        float zs = acc[t+4][r] + hi16f(vdu[r][t]) + hi16f(vsu[r][t]) + bso[t];
        float m = sigm(zf) * sofp(zs) * wd[r];
        atomicAdd(&aout[(size_t)dN[r]*FF + t*16 + c], m);
      }
    }
  }
}

// ---------------------------------------------------------------------------
// k3: per-node fc1 partials on UPDATED node features.
// ---------------------------------------------------------------------------
__global__ __launch_bounds__(256) void k3_cpre(
    const float* __restrict__ aout, const float* __restrict__ fc1w,
    float* __restrict__ C)
{
  __shared__ float wT[64*32];
  __shared__ float xs[4][64];
  int tid = threadIdx.x;
  for (int i = tid; i < 64*28; i += 256) {
    int k = i / 28, j = i % 28;
    wT[k*32 + j] = (j < 14) ? fc1w[j*ZD + k] : fc1w[(j-14)*ZD + 64 + k];
  }
  __syncthreads();
  int o  = tid & 63;
  int lw = tid >> 6;
  int wid = blockIdx.x * 4 + lw;
  int nw  = gridDim.x * 4;
  for (int n = wid; n < NN; n += nw) {
    xs[lw][o] = aout[(size_t)n*FF + o];
    float acc = 0.f;
    if (o < 28) {
      for (int k = 0; k < 64; k++) acc += xs[lw][k] * wT[k*32 + o];
      C[n*28 + o] = acc;
    }
  }
}

// ---------------------------------------------------------------------------
// k5: edge-update MLP. 8 edges/wave. Stash read + final eout write both
// non-temporal (zero-reuse streams).
// ---------------------------------------------------------------------------
__global__ __launch_bounds__(256) void k5_edge_mlp(
    const int* __restrict__ eidx,
    const float* __restrict__ fc1b,
    const float* __restrict__ fc2w, const float* __restrict__ fc2b,
    const float* __restrict__ C, float* __restrict__ eout)
{
  __shared__ float w2T[14*64];
  __shared__ float hs[4][128];
  int tid = threadIdx.x;
  for (int i = tid; i < 14*64; i += 256) {
    int j = i >> 6, o = i & 63;
    w2T[i] = fc2w[o*14 + j];
  }
  __syncthreads();
  int o  = tid & 63;
  int lw = tid >> 6;
  int j4 = o >> 2, q = o & 3;
  int wid = blockIdx.x*4 + lw;
  int nw  = gridDim.x*4;
  for (int g = wid; g < NE/8; g += nw) {
    int e0 = g*8;
    #pragma unroll
    for (int pass = 0; pass < 2; pass++) {
      int ee = pass*4 + q;
      int e = e0 + ee;
      if (j4 < 14) {
        int sN = eidx[e], dN = eidx[NE+e];
        float st = __builtin_nontemporal_load(&eout[(size_t)e*FF + j4]);
        float h = st + C[sN*28 + j4] + C[dN*28 + 14 + j4] + fc1b[j4];
        hs[lw][ee*16 + j4] = fsilu(h);
      }
    }
    asm volatile("s_waitcnt lgkmcnt(0)" ::: "memory");  // in-wave LDS RAW
    float b2 = fc2b[o];
    #pragma unroll
    for (int ee = 0; ee < 8; ee++) {
      float acc = b2;
      #pragma unroll
      for (int jj = 0; jj < 14; jj++)
        acc += w2T[jj*64 + o] * hs[lw][ee*16 + jj];
      __builtin_nontemporal_store(fsilu(acc), &eout[(size_t)(e0 + ee)*FF + o]);
    }
  }
}

// ---------------------------------------------------------------------------
extern "C" void kernel_launch(void* const* d_in, const int* in_sizes, int n_in,
                              void* d_out, int out_size, void* d_ws, size_t ws_size,
                              hipStream_t stream) {
  const float* atom  = (const float*)d_in[0];
  const int*   eidx  = (const int*)  d_in[1];
  const float* efea  = (const float*)d_in[2];
  const float* dist  = (const float*)d_in[4];
  const float* wf    = (const float*)d_in[6];
  const float* bf    = (const float*)d_in[7];
  const float* ws    = (const float*)d_in[8];
  const float* bs    = (const float*)d_in[9];
  const float* fc1w  = (const float*)d_in[10];
  const float* fc1b  = (const float*)d_in[11];
  const float* fc2w  = (const float*)d_in[12];
  const float* fc2b  = (const float*)d_in[13];

  float* aout = (float*)d_out;                 // [50000, 64]
  float* eout = aout + (size_t)NN * FF;        // [800000, 64]

  unsigned* P2u = (unsigned*)d_ws;                              // 25.6 MB
  float*    C   = (float*)((char*)d_ws + (size_t)NN * 128 * 4); // +5.6 MB

  hipLaunchKernelGGL(k1_node_pre, dim3(512), dim3(256), 0, stream,
                     atom, wf, ws, P2u, aout);
  hipLaunchKernelGGL(k2_msg, dim3(1024), dim3(256), 0, stream,
                     eidx, efea, dist, wf, ws, bf, bs, fc1w, P2u, aout, eout);
  hipLaunchKernelGGL(k3_cpre, dim3(512), dim3(256), 0, stream,
                     aout, fc1w, C);
  hipLaunchKernelGGL(k5_edge_mlp, dim3(2048), dim3(256), 0, stream,
                     eidx, fc1b, fc2w, fc2b, C, eout);
}